// Round 7
// baseline (602.439 us; speedup 1.0000x reference)
//
#include <hip/hip_runtime.h>
#include <hip/hip_bf16.h>
#include <stdint.h>

// Round 7: flash is LDS-read-issue bound (34 ds_read_b128 per 32 MFMA in the
// 16-row/wave shape; per-CU model 5.4K LDS cyc vs 0.6K MFMA cyc per iter).
// Fix: back to the 32-row/wave body (0.56 reads/MFMA — every kfr/vf feeds 2
// MFMAs) and force 3 waves/SIMD with __launch_bounds__(256,3): allocator must
// shave ~4 regs from the natural 172, trivially rematerializable (round 4's
// catastrophic spill was a 44-reg forced cut — different regime).
//
// ws layout:
//   xb      [8192][1024] bf16  @ 0         (dead after qkv -> Ob)
//   wqkv_t  [3072][1024] bf16  @ 16777216
//   wout_t  [1024][1024] bf16  @ 23068672
//   Qs      [16][4096][128]    @ 25165824
//   Ks      [16][4096][128]    @ 41943040
//   Vt      [16][128][4096]    @ 58720256

typedef __attribute__((ext_vector_type(8))) short short8;
typedef __attribute__((ext_vector_type(4))) float f32x4;

#define SCALE_Q 0.03125f

__device__ __forceinline__ unsigned short f2bf(float f) {
  union { float f; unsigned int u; } v;
  v.f = f;
  return (unsigned short)((v.u + 0x7fffu + ((v.u >> 16) & 1u)) >> 16);
}

__device__ __forceinline__ unsigned int pkbf2(float a, float b) {
  __hip_bfloat162 h = __float22bfloat162_rn(make_float2(a, b));
  union { __hip_bfloat162 h; unsigned int u; } c;
  c.h = h;
  return c.u;
}

__device__ __forceinline__ void gload_lds16(const void* g, void* l) {
  __builtin_amdgcn_global_load_lds(
      (const __attribute__((address_space(1))) uint32_t*)(uintptr_t)g,
      (__attribute__((address_space(3))) uint32_t*)(uintptr_t)l, 16, 0, 0);
}

__device__ __forceinline__ f32x4 zero4() {
  f32x4 z; z.x = 0.f; z.y = 0.f; z.z = 0.f; z.w = 0.f; return z;
}

// ---------------- conversions ----------------
__global__ __launch_bounds__(256) void k_cvt_x(const float* __restrict__ in,
                                               unsigned short* __restrict__ out) {
  const int t = blockIdx.x * 256 + threadIdx.x;
  const float4 v = ((const float4*)in)[t];
  ushort4 o;
  o.x = f2bf(v.x); o.y = f2bf(v.y); o.z = f2bf(v.z); o.w = f2bf(v.w);
  ((ushort4*)out)[t] = o;
}

__global__ __launch_bounds__(256) void k_cvt_wt(const float* __restrict__ w,
                                                unsigned short* __restrict__ wt,
                                                int Nn) {
  __shared__ float t[32][33];
  const int n0 = blockIdx.x << 5, k0 = blockIdx.y << 5;
  const int c = threadIdx.x & 31, r8 = threadIdx.x >> 5;
#pragma unroll
  for (int i = 0; i < 4; ++i) {
    const int r = (i << 3) + r8;
    t[r][c] = w[(long)(k0 + r) * Nn + n0 + c];
  }
  __syncthreads();
#pragma unroll
  for (int i = 0; i < 4; ++i) {
    const int r = (i << 3) + r8;
    wt[(long)(n0 + r) * 1024 + k0 + c] = f2bf(t[c][r]);
  }
}

// ---------------- QKV GEMM ----------------
// Q/K tiles: acc^T = mfma(bfr, afr) -> lane reg-quad = 4 consecutive d ->
// packed 8B stores. V tiles: normal orientation -> reg-quad = 4 consecutive
// m (= Vt fast axis) -> writes Vt directly.
__global__ __launch_bounds__(256, 2) void k_qkv_gemm(
    const unsigned short* __restrict__ A,   // [8192][1024]
    const unsigned short* __restrict__ Bt,  // [3072][1024]
    unsigned short* __restrict__ Qs, unsigned short* __restrict__ Ks,
    unsigned short* __restrict__ Vt) {
  __shared__ __align__(16) unsigned short lA[4][128][8];
  __shared__ __align__(16) unsigned short lB[4][128][8];
  const int tid = threadIdx.x;
  const int w = tid >> 6, ln = tid & 63;
  const int m15 = ln & 15, q4 = ln >> 4;
  const int wm = (w >> 1) << 6, wn = (w & 1) << 6;
  const int tn = blockIdx.x, tm = blockIdx.y;
  const int which = tn >> 3;   // 0=Q 1=K 2=V (uniform per block)
  const int h = tn & 7;

  f32x4 acc[4][4];
#pragma unroll
  for (int i = 0; i < 4; ++i)
#pragma unroll
    for (int j = 0; j < 4; ++j) acc[i][j] = zero4();

  if (which == 2) {
    for (int kb = 0; kb < 1024; kb += 32) {
      __syncthreads();
#pragma unroll
      for (int c = 0; c < 2; ++c) {
        const int p = ((c * 4 + w) << 10) + (ln << 4);
        const int g = p >> 11;
        const int r = (p & 2047) >> 4;
        gload_lds16(A + ((long)tm * 128 + r) * 1024 + kb + g * 8,
                    (char*)&lA[0][0][0] + p);
        gload_lds16(Bt + ((long)tn * 128 + r) * 1024 + kb + g * 8,
                    (char*)&lB[0][0][0] + p);
      }
      __syncthreads();
      short8 afr[4], bfr[4];
#pragma unroll
      for (int i = 0; i < 4; ++i)
        afr[i] = *(const short8*)&lA[q4][wm + i * 16 + m15][0];
#pragma unroll
      for (int j = 0; j < 4; ++j)
        bfr[j] = *(const short8*)&lB[q4][wn + j * 16 + m15][0];
#pragma unroll
      for (int i = 0; i < 4; ++i)
#pragma unroll
        for (int j = 0; j < 4; ++j)
          acc[i][j] = __builtin_amdgcn_mfma_f32_16x16x32_bf16(afr[i], bfr[j],
                                                              acc[i][j], 0, 0, 0);
    }
#pragma unroll
    for (int i = 0; i < 4; ++i) {
      const int m0 = (tm << 7) + wm + (i << 4) + (q4 << 2);
      const int b = m0 >> 12, row0 = m0 & 4095;
#pragma unroll
      for (int j = 0; j < 4; ++j) {
        const int dd = wn + (j << 4) + m15;
        const long bh = b * 8 + h;
        uint2 u;
        u.x = pkbf2(acc[i][j][0], acc[i][j][1]);
        u.y = pkbf2(acc[i][j][2], acc[i][j][3]);
        *(uint2*)&Vt[(bh * 128 + dd) * 4096 + row0] = u;
      }
    }
  } else {
    for (int kb = 0; kb < 1024; kb += 32) {
      __syncthreads();
#pragma unroll
      for (int c = 0; c < 2; ++c) {
        const int p = ((c * 4 + w) << 10) + (ln << 4);
        const int g = p >> 11;
        const int r = (p & 2047) >> 4;
        gload_lds16(A + ((long)tm * 128 + r) * 1024 + kb + g * 8,
                    (char*)&lA[0][0][0] + p);
        gload_lds16(Bt + ((long)tn * 128 + r) * 1024 + kb + g * 8,
                    (char*)&lB[0][0][0] + p);
      }
      __syncthreads();
      short8 afr[4], bfr[4];
#pragma unroll
      for (int i = 0; i < 4; ++i)
        afr[i] = *(const short8*)&lA[q4][wm + i * 16 + m15][0];
#pragma unroll
      for (int j = 0; j < 4; ++j)
        bfr[j] = *(const short8*)&lB[q4][wn + j * 16 + m15][0];
#pragma unroll
      for (int i = 0; i < 4; ++i)
#pragma unroll
        for (int j = 0; j < 4; ++j)
          acc[i][j] = __builtin_amdgcn_mfma_f32_16x16x32_bf16(bfr[j], afr[i],
                                                              acc[i][j], 0, 0, 0);
    }
    unsigned short* Dst = (which == 0) ? Qs : Ks;
    const float sc = (which == 0) ? SCALE_Q : 1.0f;
#pragma unroll
    for (int i = 0; i < 4; ++i) {
      const int m = (tm << 7) + wm + (i << 4) + m15;
      const int b = m >> 12, row = m & 4095;
      const long bh = b * 8 + h;
#pragma unroll
      for (int j = 0; j < 4; ++j) {
        const int dd0 = wn + (j << 4) + (q4 << 2);
        uint2 u;
        u.x = pkbf2(acc[i][j][0] * sc, acc[i][j][1] * sc);
        u.y = pkbf2(acc[i][j][2] * sc, acc[i][j][3] * sc);
        *(uint2*)&Dst[(bh * 4096 + row) * 128 + dd0] = u;
      }
    }
  }
}

// ---------------- flash attention (S^T, 128 rows/block, 32 rows/wave) ---
// grid (32 rowblk, 16 bh); 256 thr = 4 waves x 32 rows (two 16-row groups).
// 36 ds_read_b128 per 64 MFMA per wave-iter (0.56 reads/MFMA — the LDS-issue
// optimum of the shapes tried). launch_bounds(256,3): cap ~170 regs/wave ->
// 3 waves/SIMD (natural allocation was 172 -> 2/SIMD).
__global__ __launch_bounds__(256, 3) void k_flash(
    const unsigned short* __restrict__ Qs, const unsigned short* __restrict__ Ks,
    const unsigned short* __restrict__ Vt, const int* __restrict__ mask,
    unsigned short* __restrict__ Ob) {
  __shared__ __align__(16) unsigned short lK[16][64][8];   // 16 KB
  __shared__ __align__(16) unsigned short lV[8][128][8];   // 16 KB
  __shared__ __align__(16) unsigned short lP[4][32][72];   // 18 KB

  const int tid = threadIdx.x;
  const int w = tid >> 6, ln = tid & 63;
  const int m15 = ln & 15, q4 = ln >> 4;
  const int rowblk = blockIdx.x, bh = blockIdx.y;
  const int rbase = rowblk * 128 + w * 32;

  const unsigned short* Qbh = Qs + (long)bh * 524288;
  const unsigned short* Kbh = Ks + (long)bh * 524288;
  const unsigned short* Vbh = Vt + (long)bh * 524288;

  short8 qf[2][4];
#pragma unroll
  for (int i = 0; i < 2; ++i)
#pragma unroll
    for (int kk = 0; kk < 4; ++kk)
      qf[i][kk] = *(const short8*)(Qbh +
          (long)(rbase + i * 16 + m15) * 128 + kk * 32 + q4 * 8);

  f32x4 o[2][8];
#pragma unroll
  for (int i = 0; i < 2; ++i)
#pragma unroll
    for (int j = 0; j < 8; ++j) o[i][j] = zero4();
  f32x4 lacc[2];
  lacc[0] = zero4(); lacc[1] = zero4();

  const bool maskblk = rowblk < 16;

  for (int kv = 0; kv < 4096; kv += 64) {
    __syncthreads();
#pragma unroll
    for (int c = 0; c < 4; ++c) {
      const int p = ((c * 4 + w) << 10) + (ln << 4);
      const int cs = p >> 10;
      const int j = (p & 1023) >> 4;
      gload_lds16(Kbh + (long)(kv + j) * 128 + cs * 8, (char*)&lK[0][0][0] + p);
      const int cv = p >> 11;
      const int dv = (p & 2047) >> 4;
      gload_lds16(Vbh + (long)dv * 4096 + kv + cv * 8, (char*)&lV[0][0][0] + p);
    }
    __syncthreads();

    // S^T = K Q^T : s[i][jt][r] = S[q = rbase+i*16+m15][j = kv+jt*16+q4*4+r]
    f32x4 s[2][4];
#pragma unroll
    for (int i = 0; i < 2; ++i)
#pragma unroll
      for (int jt = 0; jt < 4; ++jt) s[i][jt] = zero4();
#pragma unroll
    for (int jt = 0; jt < 4; ++jt) {
      short8 kfr[4];
#pragma unroll
      for (int kk = 0; kk < 4; ++kk)
        kfr[kk] = *(const short8*)&lK[kk * 4 + q4][jt * 16 + m15][0];
#pragma unroll
      for (int i = 0; i < 2; ++i)
#pragma unroll
        for (int kk = 0; kk < 4; ++kk)
          s[i][jt] = __builtin_amdgcn_mfma_f32_16x16x32_bf16(kfr[kk], qf[i][kk],
                                                             s[i][jt], 0, 0, 0);
    }

    if (maskblk && kv < 2048) {
#pragma unroll
      for (int i = 0; i < 2; ++i) {
        const int qrow = rbase + i * 16 + m15;
#pragma unroll
        for (int jt = 0; jt < 4; ++jt) {
          const int4 mv =
              *(const int4*)&mask[(long)qrow * 2048 + kv + jt * 16 + q4 * 4];
          s[i][jt].x = mv.x ? s[i][jt].x : -1e30f;
          s[i][jt].y = mv.y ? s[i][jt].y : -1e30f;
          s[i][jt].z = mv.z ? s[i][jt].z : -1e30f;
          s[i][jt].w = mv.w ? s[i][jt].w : -1e30f;
        }
      }
    }

    // p = exp(s); per-lane l; pack to wave-private LDS as PV A-frags.
#pragma unroll
    for (int i = 0; i < 2; ++i) {
#pragma unroll
      for (int jt = 0; jt < 4; ++jt) {
        f32x4 p;
        p.x = __expf(s[i][jt].x); p.y = __expf(s[i][jt].y);
        p.z = __expf(s[i][jt].z); p.w = __expf(s[i][jt].w);
        lacc[i].x += p.x; lacc[i].y += p.y;
        lacc[i].z += p.z; lacc[i].w += p.w;
        uint2 u;
        u.x = pkbf2(p.x, p.y);
        u.y = pkbf2(p.z, p.w);
        *(uint2*)&lP[w][i * 16 + m15][jt * 16 + q4 * 4] = u;
      }
    }
    __asm__ volatile("s_waitcnt lgkmcnt(0)" ::: "memory");

    // O += P @ V  (each vf read feeds both i row-groups)
#pragma unroll
    for (int kk2 = 0; kk2 < 2; ++kk2) {
      short8 pf[2];
#pragma unroll
      for (int i = 0; i < 2; ++i)
        pf[i] = *(const short8*)&lP[w][i * 16 + m15][kk2 * 32 + q4 * 8];
#pragma unroll
      for (int jt2 = 0; jt2 < 8; ++jt2) {
        const short8 vf = *(const short8*)&lV[kk2 * 4 + q4][jt2 * 16 + m15][0];
#pragma unroll
        for (int i = 0; i < 2; ++i)
          o[i][jt2] = __builtin_amdgcn_mfma_f32_16x16x32_bf16(pf[i], vf,
                                                              o[i][jt2], 0, 0, 0);
      }
    }
  }

  const int b = bh >> 3, h = bh & 7;
#pragma unroll
  for (int i = 0; i < 2; ++i) {
    float lh = lacc[i].x + lacc[i].y + lacc[i].z + lacc[i].w;
    lh += __shfl_xor(lh, 16);
    lh += __shfl_xor(lh, 32);
    const float linv = 1.0f / lh;
    float linv_r[4];
#pragma unroll
    for (int r = 0; r < 4; ++r) linv_r[r] = __shfl(linv, q4 * 4 + r);
#pragma unroll
    for (int r = 0; r < 4; ++r) {
      const int row = rbase + i * 16 + q4 * 4 + r;
      unsigned short* op = Ob + ((long)(b * 4096 + row)) * 1024 + h * 128;
#pragma unroll
      for (int jt2 = 0; jt2 < 8; ++jt2)
        op[jt2 * 16 + m15] = f2bf(o[i][jt2][r] * linv_r[r]);
    }
  }
}

// ---------------- out projection ----------------
__global__ __launch_bounds__(256, 2) void k_proj_gemm(
    const unsigned short* __restrict__ A,   // [8192][1024]
    const unsigned short* __restrict__ Bt,  // [1024][1024]
    const float* __restrict__ bias, float* __restrict__ Out) {
  __shared__ __align__(16) unsigned short lA[4][128][8];
  __shared__ __align__(16) unsigned short lB[4][128][8];
  const int tid = threadIdx.x;
  const int w = tid >> 6, ln = tid & 63;
  const int m15 = ln & 15, q4 = ln >> 4;
  const int wm = (w >> 1) << 6, wn = (w & 1) << 6;
  const int tn = blockIdx.x, tm = blockIdx.y;

  f32x4 acc[4][4];
#pragma unroll
  for (int i = 0; i < 4; ++i)
#pragma unroll
    for (int j = 0; j < 4; ++j) acc[i][j] = zero4();

  for (int kb = 0; kb < 1024; kb += 32) {
    __syncthreads();
#pragma unroll
    for (int c = 0; c < 2; ++c) {
      const int p = ((c * 4 + w) << 10) + (ln << 4);
      const int g = p >> 11;
      const int r = (p & 2047) >> 4;
      gload_lds16(A + ((long)tm * 128 + r) * 1024 + kb + g * 8,
                  (char*)&lA[0][0][0] + p);
      gload_lds16(Bt + ((long)tn * 128 + r) * 1024 + kb + g * 8,
                  (char*)&lB[0][0][0] + p);
    }
    __syncthreads();
    short8 afr[4], bfr[4];
#pragma unroll
    for (int i = 0; i < 4; ++i)
      afr[i] = *(const short8*)&lA[q4][wm + i * 16 + m15][0];
#pragma unroll
    for (int j = 0; j < 4; ++j)
      bfr[j] = *(const short8*)&lB[q4][wn + j * 16 + m15][0];
#pragma unroll
    for (int i = 0; i < 4; ++i)
#pragma unroll
      for (int j = 0; j < 4; ++j)
        acc[i][j] = __builtin_amdgcn_mfma_f32_16x16x32_bf16(afr[i], bfr[j],
                                                            acc[i][j], 0, 0, 0);
  }

#pragma unroll
  for (int i = 0; i < 4; ++i)
#pragma unroll
    for (int r = 0; r < 4; ++r) {
      const int m = (tm << 7) + wm + (i << 4) + (q4 << 2) + r;
#pragma unroll
      for (int j = 0; j < 4; ++j) {
        const int n = (tn << 7) + wn + (j << 4) + m15;
        Out[(long)m * 1024 + n] = acc[i][j][r] + bias[n];
      }
    }
}

extern "C" void kernel_launch(void* const* d_in, const int* in_sizes, int n_in,
                              void* d_out, int out_size, void* d_ws,
                              size_t ws_size, hipStream_t stream) {
  const float* x = (const float*)d_in[0];
  const float* Wqkv = (const float*)d_in[1];
  const float* Wout = (const float*)d_in[2];
  const float* bout = (const float*)d_in[3];
  const int* mask = (const int*)d_in[4];
  float* out = (float*)d_out;

  char* ws = (char*)d_ws;
  unsigned short* xb     = (unsigned short*)(ws);            // later Ob
  unsigned short* wqkv_t = (unsigned short*)(ws + 16777216);
  unsigned short* wout_t = (unsigned short*)(ws + 23068672);
  unsigned short* Qs     = (unsigned short*)(ws + 25165824);
  unsigned short* Ks     = (unsigned short*)(ws + 41943040);
  unsigned short* Vt     = (unsigned short*)(ws + 58720256);
  unsigned short* Ob     = xb;  // xb dead after qkv_gemm

  hipLaunchKernelGGL(k_cvt_x, dim3(8192), dim3(256), 0, stream, x, xb);
  hipLaunchKernelGGL(k_cvt_wt, dim3(96, 32), dim3(256), 0, stream, Wqkv, wqkv_t, 3072);
  hipLaunchKernelGGL(k_cvt_wt, dim3(32, 32), dim3(256), 0, stream, Wout, wout_t, 1024);
  hipLaunchKernelGGL(k_qkv_gemm, dim3(24, 64), dim3(256), 0, stream,
                     xb, wqkv_t, Qs, Ks, Vt);
  hipLaunchKernelGGL(k_flash, dim3(32, 16), dim3(256), 0, stream,
                     Qs, Ks, Vt, mask, Ob);
  hipLaunchKernelGGL(k_proj_gemm, dim3(8, 64), dim3(256), 0, stream,
                     Ob, wout_t, bout, out);
}